// Round 1
// baseline (1717.924 us; speedup 1.0000x reference)
//
#include <hip/hip_runtime.h>

#define NN 2000000
#define DD 128
#define BB 1024
#define STEPS 3

// ---------------- prep: transpose weights + combine bias (runs once) --------
// WT[k][j] (k in [0,384), j in [0,512)):
//   k <  256: W_ih[j][k]      (W_ih is [512,256] row-major)
//   k >= 256: W_hh[j][k-256]  (W_hh is [512,128] row-major)
__global__ void prep_kernel(const float* __restrict__ W_ih,
                            const float* __restrict__ W_hh,
                            const float* __restrict__ b_ih,
                            const float* __restrict__ b_hh,
                            float* __restrict__ WT, float* __restrict__ bias) {
    int idx = blockIdx.x * blockDim.x + threadIdx.x;
    if (idx < 384 * 512) {
        int k = idx >> 9;
        int j = idx & 511;
        WT[idx] = (k < 256) ? W_ih[j * 256 + k] : W_hh[j * 128 + (k - 256)];
    }
    if (idx < 512) bias[idx] = b_ih[idx] + b_hh[idx];
}

// ---------------- segment starts (runs once) --------------------------------
// start[b] = first node index with batch_index >= b ; start[BB] = NN
__global__ void segstart_kernel(const int* __restrict__ bi, int* __restrict__ start) {
    int n = blockIdx.x * blockDim.x + threadIdx.x;
    if (n >= NN) return;
    int v = bi[n];
    int p = (n == 0) ? -1 : bi[n - 1];
    for (int t = p + 1; t <= v; ++t) start[t] = n;
    if (n == NN - 1) {
        for (int t = v + 1; t <= BB; ++t) start[t] = NN;
    }
}

// ---------------- LSTM cell (per step) ---------------------------------------
// gates[b][j] = sum_k in[b][k] * WT[k][j] + bias[j],  in[b] = [q_star[b] | h[b]]
// 256 blocks x 256 threads; each block handles 4 b-rows; thread j computes
// j0=tid, j1=tid+256 for all 4 rows.
__device__ __forceinline__ float sigmoid_f(float x) { return 1.0f / (1.0f + __expf(-x)); }
__device__ __forceinline__ float tanh_f(float x) {
    float e = __expf(2.0f * x);
    return 1.0f - 2.0f / (e + 1.0f);   // saturates cleanly, no NaN
}

__launch_bounds__(256)
__global__ void lstm_kernel(const float* __restrict__ q_star,
                            float* __restrict__ h, float* __restrict__ c,
                            const float* __restrict__ WT,
                            const float* __restrict__ bias) {
    __shared__ float in_lds[4][384];
    __shared__ float gate_lds[4][512];
    const int b0 = blockIdx.x * 4;
    const int tid = threadIdx.x;

    // stage inputs: 4 rows x 384
    for (int idx = tid; idx < 4 * 384; idx += 256) {
        int bb = idx / 384;
        int k = idx - bb * 384;
        in_lds[bb][k] = (k < 256) ? q_star[(b0 + bb) * 256 + k]
                                  : h[(b0 + bb) * 128 + (k - 256)];
    }
    __syncthreads();

    const int j0 = tid, j1 = tid + 256;
    float acc[4][2] = {};
    for (int k = 0; k < 384; k += 4) {
        float4 a0 = *(const float4*)&in_lds[0][k];
        float4 a1 = *(const float4*)&in_lds[1][k];
        float4 a2 = *(const float4*)&in_lds[2][k];
        float4 a3 = *(const float4*)&in_lds[3][k];
        const float* f0 = (const float*)&a0;
        const float* f1 = (const float*)&a1;
        const float* f2 = (const float*)&a2;
        const float* f3 = (const float*)&a3;
#pragma unroll
        for (int kk = 0; kk < 4; ++kk) {
            float w0 = WT[(k + kk) * 512 + j0];
            float w1 = WT[(k + kk) * 512 + j1];
            acc[0][0] = fmaf(f0[kk], w0, acc[0][0]);
            acc[0][1] = fmaf(f0[kk], w1, acc[0][1]);
            acc[1][0] = fmaf(f1[kk], w0, acc[1][0]);
            acc[1][1] = fmaf(f1[kk], w1, acc[1][1]);
            acc[2][0] = fmaf(f2[kk], w0, acc[2][0]);
            acc[2][1] = fmaf(f2[kk], w1, acc[2][1]);
            acc[3][0] = fmaf(f3[kk], w0, acc[3][0]);
            acc[3][1] = fmaf(f3[kk], w1, acc[3][1]);
        }
    }
    float bj0 = bias[j0], bj1 = bias[j1];
#pragma unroll
    for (int bb = 0; bb < 4; ++bb) {
        gate_lds[bb][j0] = acc[bb][0] + bj0;
        gate_lds[bb][j1] = acc[bb][1] + bj1;
    }
    __syncthreads();

    // pointwise LSTM update: 4 b x 128 d = 512 items, 2 per thread
#pragma unroll
    for (int it = 0; it < 2; ++it) {
        int item = tid + it * 256;
        int bb = item >> 7;
        int d = item & 127;
        int b = b0 + bb;
        float gi = gate_lds[bb][d];
        float gf = gate_lds[bb][128 + d];
        float gg = gate_lds[bb][256 + d];
        float go = gate_lds[bb][384 + d];
        float cn = sigmoid_f(gf) * c[b * 128 + d] + sigmoid_f(gi) * tanh_f(gg);
        float hn = sigmoid_f(go) * tanh_f(cn);
        c[b * 128 + d] = cn;
        h[b * 128 + d] = hn;
    }
}

// ---------------- attention + pooling (per step) ------------------------------
// One block per graph. 4 waves; each wave = two 32-lane halves; each half runs
// two independent online-softmax streams (A,B) -> 16 partials merged in LDS.
__launch_bounds__(256)
__global__ void att_kernel(const float* __restrict__ x,
                           const float* __restrict__ h,
                           const int* __restrict__ start,
                           float* __restrict__ q_star) {
    const int b = blockIdx.x;
    const int tid = threadIdx.x;
    const int wave = tid >> 6;
    const int lane = tid & 63;
    const int half = lane >> 5;
    const int sl = lane & 31;

    const int s0 = start[b];
    const int s1 = start[b + 1];

    // q fragment: channels 4*sl .. 4*sl+3 (q = h[b])
    float4 qv = *(const float4*)&h[b * 128 + 4 * sl];

    float mA = -1e30f, sA = 0.0f;
    float4 rA = make_float4(0.f, 0.f, 0.f, 0.f);
    float mB = -1e30f, sB = 0.0f;
    float4 rB = make_float4(0.f, 0.f, 0.f, 0.f);

    for (int n0 = s0 + wave * 4; n0 < s1; n0 += 16) {
        int nA = n0 + half;
        int nB = n0 + 2 + half;
        bool vA = nA < s1;
        bool vB = nB < s1;
        float4 xa = make_float4(0.f, 0.f, 0.f, 0.f);
        float4 xb = make_float4(0.f, 0.f, 0.f, 0.f);
        if (vA) xa = *(const float4*)&x[(size_t)nA * 128 + 4 * sl];
        if (vB) xb = *(const float4*)&x[(size_t)nB * 128 + 4 * sl];

        float dA = xa.x * qv.x + xa.y * qv.y + xa.z * qv.z + xa.w * qv.w;
        float dB = xb.x * qv.x + xb.y * qv.y + xb.z * qv.z + xb.w * qv.w;
#pragma unroll
        for (int off = 16; off >= 1; off >>= 1) {
            dA += __shfl_xor(dA, off, 64);
            dB += __shfl_xor(dB, off, 64);
        }
        // stream A update
        {
            float e = vA ? dA : -1e30f;
            float nm = fmaxf(mA, e);
            float fac = __expf(mA - nm);
            float w = vA ? __expf(e - nm) : 0.0f;
            sA = sA * fac + w;
            rA.x = rA.x * fac + w * xa.x;
            rA.y = rA.y * fac + w * xa.y;
            rA.z = rA.z * fac + w * xa.z;
            rA.w = rA.w * fac + w * xa.w;
            mA = nm;
        }
        // stream B update
        {
            float e = vB ? dB : -1e30f;
            float nm = fmaxf(mB, e);
            float fac = __expf(mB - nm);
            float w = vB ? __expf(e - nm) : 0.0f;
            sB = sB * fac + w;
            rB.x = rB.x * fac + w * xb.x;
            rB.y = rB.y * fac + w * xb.y;
            rB.z = rB.z * fac + w * xb.z;
            rB.w = rB.w * fac + w * xb.w;
            mB = nm;
        }
    }

    // merge 16 partials
    __shared__ float m_sh[16];
    __shared__ float s_sh[16];
    __shared__ float r_sh[16][128];

    int slotA = wave * 4 + half * 2;
    int slotB = slotA + 1;
    *(float4*)&r_sh[slotA][4 * sl] = rA;
    *(float4*)&r_sh[slotB][4 * sl] = rB;
    if (sl == 0) {
        m_sh[slotA] = mA;
        s_sh[slotA] = sA;
        m_sh[slotB] = mB;
        s_sh[slotB] = sB;
    }
    __syncthreads();

    if (tid < 128) {
        int d = tid;
        float M = -1e30f;
#pragma unroll
        for (int p = 0; p < 16; ++p) M = fmaxf(M, m_sh[p]);
        float S = 0.0f, R = 0.0f;
#pragma unroll
        for (int p = 0; p < 16; ++p) {
            float fac = __expf(m_sh[p] - M);
            S += s_sh[p] * fac;
            R += r_sh[p][d] * fac;
        }
        float rfin = R / (S + 1e-16f);
        q_star[b * 256 + d] = h[b * 128 + d];
        q_star[b * 256 + 128 + d] = rfin;
    }
}

// ---------------- launch ------------------------------------------------------
extern "C" void kernel_launch(void* const* d_in, const int* in_sizes, int n_in,
                              void* d_out, int out_size, void* d_ws, size_t ws_size,
                              hipStream_t stream) {
    const float* x    = (const float*)d_in[0];
    const int*   bidx = (const int*)d_in[1];
    const float* W_ih = (const float*)d_in[2];
    const float* W_hh = (const float*)d_in[3];
    const float* b_ih = (const float*)d_in[4];
    const float* b_hh = (const float*)d_in[5];
    float* q_star = (float*)d_out;   // [B, 2D] — doubles as the output

    char* ws = (char*)d_ws;
    float* WT    = (float*)(ws);                    // 384*512*4 = 786432 B
    float* bias  = (float*)(ws + 786432);           // 2048 B
    float* h     = (float*)(ws + 788480);           // 1024*128*4 = 524288 B
    float* c     = (float*)(ws + 1312768);          // 524288 B
    int*   start = (int*)  (ws + 1837056);          // (B+1)*4

    hipMemsetAsync(h, 0, BB * DD * sizeof(float), stream);
    hipMemsetAsync(c, 0, BB * DD * sizeof(float), stream);
    hipMemsetAsync(q_star, 0, BB * 2 * DD * sizeof(float), stream);

    prep_kernel<<<(384 * 512 + 255) / 256, 256, 0, stream>>>(W_ih, W_hh, b_ih, b_hh, WT, bias);
    segstart_kernel<<<(NN + 255) / 256, 256, 0, stream>>>(bidx, start);

    for (int step = 0; step < STEPS; ++step) {
        lstm_kernel<<<256, 256, 0, stream>>>(q_star, h, c, WT, bias);
        att_kernel<<<BB, 256, 0, stream>>>(x, h, start, q_star);
    }
}